// Round 1
// baseline (521.325 us; speedup 1.0000x reference)
//
#include <hip/hip_runtime.h>
#include <math.h>

namespace {

constexpr int NATOM = 512;
constexpr int BT    = 16;            // neighbor tile
constexpr int NT    = NATOM / BT;    // 32 tiles

struct Ptrs { const float* p[19]; };

// input index map:
// 0 geometry [512,3]; 1 x0 [512,32,1]; 2 x1 [512,32,3]
// then per net q in {f0,fa,fb,fc}: 3+4q w1[64,64]; 4+4q b1[64]; 5+4q w2[32,64]; 6+4q b2[32]

__global__ __launch_bounds__(256, 2)
void tfn_fused(Ptrs A, float* __restrict__ out) {
  const int a   = blockIdx.x;
  const int tid = threadIdx.x;

  __shared__ __align__(16) float rbf_lds[BT][64];    // 4 KB
  __shared__ __align__(16) float h_lds[BT][256];     // 16 KB (4 nets x 64 hidden)
  __shared__ __align__(16) float rad_lds[BT][128];   // 8 KB (4 nets x 32 ch)
  __shared__ __align__(16) float u_lds[BT][4];       // unit vectors
  __shared__ __align__(16) float x0_lds[BT * 32];    // 2 KB
  __shared__ __align__(16) float x1_lds[BT * 96];    // 6 KB
  __shared__ __align__(16) float scr[96][5];         // partial-sum combine

  const float* __restrict__ geom = A.p[0];
  const float* __restrict__ x0g  = A.p[1];
  const float* __restrict__ x1g  = A.p[2];

  // ---------- persistent per-thread weights (registers) ----------
  // stage-1 role: thread owns hidden row j1 of net1 (256 rows total)
  const int net1 = tid >> 6, j1 = tid & 63;
  float w1row[64];
  {
    const float* w1p = A.p[3 + 4 * net1] + j1 * 64;
    #pragma unroll
    for (int q = 0; q < 16; ++q) {
      const float4 v = *(const float4*)(w1p + 4 * q);
      w1row[4*q+0] = v.x; w1row[4*q+1] = v.y; w1row[4*q+2] = v.z; w1row[4*q+3] = v.w;
    }
  }
  const float b1v = A.p[4 + 4 * net1][j1];

  // stage-2 role: thread pair (bh2) owns output channel ccat (128 total)
  const int ccat = tid & 127, bh2 = tid >> 7;
  const int net2 = ccat >> 5, c2 = ccat & 31;
  float w2row[64];
  {
    const float* w2p = A.p[5 + 4 * net2] + c2 * 64;
    #pragma unroll
    for (int q = 0; q < 16; ++q) {
      const float4 v = *(const float4*)(w2p + 4 * q);
      w2row[4*q+0] = v.x; w2row[4*q+1] = v.y; w2row[4*q+2] = v.z; w2row[4*q+3] = v.w;
    }
  }
  const float b2v = A.p[6 + 4 * net2][c2];

  const float gax = geom[3*a+0], gay = geom[3*a+1], gaz = geom[3*a+2];

  // stage-3 role: threads 0..191 -> (b-half, channel c3, component i3)
  const bool act3 = (tid < 192);
  const int  t3   = (tid < 96) ? tid : tid - 96;   // partner mapping
  const int  bh3  = (tid >= 96) ? 1 : 0;
  const int  c3   = t3 & 31;
  const int  i3   = t3 >> 5;           // 0..2 for active threads
  const int  j3   = (i3 + 1) % 3;
  const int  k3   = (i3 + 2) % 3;

  float o1a = 0.f, o1b = 0.f, o1c = 0.f, o0a = 0.f, o0b = 0.f;

  for (int t = 0; t < NT; ++t) {
    const int b0 = t * BT;
    __syncthreads();   // previous tile's consumers done before we overwrite LDS

    // ---------------- Phase A: rbf, unit vectors, x staging ----------------
    {
      const int bb = tid & 15;      // neighbor within tile
      const int rq = tid >> 4;      // rbf quad index 0..15
      const int bg = b0 + bb;
      const float dx = gax - geom[3*bg+0];
      const float dy = gay - geom[3*bg+1];
      const float dz = gaz - geom[3*bg+2];
      const float r2 = dx*dx + dy*dy + dz*dz;
      const float dij = sqrtf(fmaxf(r2, 1e-8f));
      const float step = 10.0f / 63.0f;
      const float d0 = dij - step * (float)(4 * rq);
      const float d1 = d0 - step;
      const float d2 = d0 - 2.f * step;
      const float d3 = d0 - 3.f * step;
      float4 e;
      e.x = __expf(-10.f * d0 * d0);
      e.y = __expf(-10.f * d1 * d1);
      e.z = __expf(-10.f * d2 * d2);
      e.w = __expf(-10.f * d3 * d3);
      *(float4*)&rbf_lds[bb][4 * rq] = e;
      if (rq == 0) {
        // reference: unit = rij / sqrt(r2 + EPS)  (exactly 0 on diagonal -> self-mask free)
        const float inv = 1.0f / sqrtf(r2 + 1e-8f);
        u_lds[bb][0] = dx * inv; u_lds[bb][1] = dy * inv; u_lds[bb][2] = dz * inv;
      }
      // stage x0/x1 tiles (coalesced)
      x0_lds[tid]       = x0g[b0 * 32 + tid];
      x0_lds[tid + 256] = x0g[b0 * 32 + tid + 256];
      #pragma unroll
      for (int k = 0; k < 6; ++k)
        x1_lds[tid + 256 * k] = x1g[b0 * 96 + tid + 256 * k];
    }
    __syncthreads();

    // ---------------- Stage 1: h[jcat][b] = relu(rbf . w1row + b1) ----------------
    #pragma unroll
    for (int b = 0; b < BT; ++b) {
      const float4* rb = (const float4*)rbf_lds[b];   // wave-uniform broadcast reads
      float s0 = 0.f, s1 = 0.f, s2 = 0.f, s3 = 0.f;
      #pragma unroll
      for (int q = 0; q < 16; ++q) {
        const float4 v = rb[q];
        s0 = fmaf(w1row[4*q+0], v.x, s0);
        s1 = fmaf(w1row[4*q+1], v.y, s1);
        s2 = fmaf(w1row[4*q+2], v.z, s2);
        s3 = fmaf(w1row[4*q+3], v.w, s3);
      }
      h_lds[b][tid] = fmaxf((s0 + s1) + (s2 + s3) + b1v, 0.0f);
    }
    __syncthreads();

    // ---------------- Stage 2: rad[ccat][b] = h . w2row + b2 ----------------
    #pragma unroll
    for (int bb = 0; bb < 8; ++bb) {
      const int b = bh2 * 8 + bb;
      const float4* hp = (const float4*)&h_lds[b][net2 * 64];  // 2-addr broadcast
      float s0 = 0.f, s1 = 0.f, s2 = 0.f, s3 = 0.f;
      #pragma unroll
      for (int q = 0; q < 16; ++q) {
        const float4 v = hp[q];
        s0 = fmaf(w2row[4*q+0], v.x, s0);
        s1 = fmaf(w2row[4*q+1], v.y, s1);
        s2 = fmaf(w2row[4*q+2], v.z, s2);
        s3 = fmaf(w2row[4*q+3], v.w, s3);
      }
      rad_lds[b][ccat] = (s0 + s1) + (s2 + s3) + b2v;
    }
    __syncthreads();

    // ---------------- Stage 3: equivariant neighbor accumulation ----------------
    if (act3) {
      #pragma unroll
      for (int bb = 0; bb < 8; ++bb) {
        const int b = bh3 * 8 + bb;
        const float r0v = rad_lds[b][c3];        // f0 radial (unmasked, incl. self)
        const float rav = rad_lds[b][32 + c3];   // fa
        const float rbv = rad_lds[b][64 + c3];   // fb
        const float rcv = rad_lds[b][96 + c3];   // fc
        const float x0v = x0_lds[b * 32 + c3];
        const float xi  = x1_lds[b * 96 + 3 * c3 + i3];
        const float xj  = x1_lds[b * 96 + 3 * c3 + j3];
        const float xk  = x1_lds[b * 96 + 3 * c3 + k3];
        const float ui  = u_lds[b][i3];
        const float uj  = u_lds[b][j3];
        const float uk  = u_lds[b][k3];
        o1b = fmaf(r0v, xi, o1b);                         // out1_b = r0 * x1
        o1a = fmaf(rav * x0v, ui, o1a);                   // out1_a = u_i * ra * x0
        o1c = fmaf(rcv, fmaf(uj, xk, -(uk * xj)), o1c);   // out1_c = rc * (u x x1)_i
        if (i3 == 0) {
          o0a = fmaf(r0v, x0v, o0a);                      // out0_a = r0 * x0
          const float dot = fmaf(ui, xi, fmaf(uj, xj, uk * xk));
          o0b = fmaf(rbv, dot, o0b);                      // out0_b = rb * (u . x1)
        }
      }
    }
  }

  // ---------------- combine b-half partials and store ----------------
  __syncthreads();
  if (tid >= 96 && tid < 192) {
    const int q = tid - 96;
    scr[q][0] = o1a; scr[q][1] = o1b; scr[q][2] = o1c; scr[q][3] = o0a; scr[q][4] = o0b;
  }
  __syncthreads();
  if (tid < 96) {
    o1a += scr[tid][0]; o1b += scr[tid][1]; o1c += scr[tid][2];
    o0a += scr[tid][3]; o0b += scr[tid][4];
    // output: out0 [512][64][1] then out1 [512][96][3]
    float* o1 = out + NATOM * 64 + a * 288;
    o1[(      c3) * 3 + i3] = o1a;
    o1[(32  + c3) * 3 + i3] = o1b;
    o1[(64  + c3) * 3 + i3] = o1c;
    if (i3 == 0) {
      out[a * 64 + c3]      = o0a;
      out[a * 64 + 32 + c3] = o0b;
    }
  }
}

} // namespace

extern "C" void kernel_launch(void* const* d_in, const int* in_sizes, int n_in,
                              void* d_out, int out_size, void* d_ws, size_t ws_size,
                              hipStream_t stream) {
  (void)in_sizes; (void)n_in; (void)d_ws; (void)ws_size; (void)out_size;
  Ptrs A;
  for (int i = 0; i < 19; ++i) A.p[i] = (const float*)d_in[i];
  tfn_fused<<<dim3(NATOM), dim3(256), 0, stream>>>(A, (float*)d_out);
}

// Round 2
// 144.081 us; speedup vs baseline: 3.6183x; 3.6183x over previous
//
#include <hip/hip_runtime.h>
#include <math.h>

namespace {

constexpr int NATOM = 512;
constexpr int BT    = 32;            // neighbor tile
constexpr int NT    = NATOM / BT;    // 16 tiles
constexpr float STEP = 10.0f / 63.0f;

typedef float f32x4 __attribute__((ext_vector_type(4)));
typedef short s16x8 __attribute__((ext_vector_type(8)));

struct Ptrs { const float* p[19]; };

// input index map:
// 0 geometry [512,3]; 1 x0 [512,32,1]; 2 x1 [512,32,3]
// then per net q in {f0,fa,fb,fc}: 3+4q w1[64,64]; 4+4q b1[64]; 5+4q w2[32,64]; 6+4q b2[32]

__device__ __forceinline__ short f2bf(float f) {
  union { float f; unsigned u; } v; v.f = f;
  const unsigned r = (v.u + 0x7fffu + ((v.u >> 16) & 1u)) >> 16;  // RNE
  return (short)r;
}

__global__ __launch_bounds__(256, 2)
void tfn_fused(Ptrs A, float* __restrict__ out) {
  const int a    = blockIdx.x;
  const int tid  = threadIdx.x;
  const int w    = tid >> 6;        // wave = net (f0,fa,fb,fc)
  const int lane = tid & 63;
  const int ln   = lane & 15;
  const int hi   = lane >> 4;       // 0..3

  // ---------------- LDS (62.2 KB total, 2 blocks/CU) ----------------
  __shared__ __align__(16) short rbf_s[BT][72];       // bf16 rbf tile, row 144B (16B-aligned)
  __shared__ __align__(16) short h_s[4][BT][72];      // per-net hidden, bf16
  __shared__ __align__(16) float radT[128][36];       // rad transposed [net*32+c][b], pad 36
  __shared__ __align__(16) float x0T[32][36];         // x0 transposed [c][b]
  __shared__ __align__(16) float x1T[96][36];         // x1 transposed [c*3+i][b]
  __shared__ __align__(16) float uT[3][36];           // unit vec [i][b]
  __shared__ __align__(16) float scr[96][5];          // partial combine

  const float* __restrict__ geom = A.p[0];
  const float* __restrict__ x0g  = A.p[1];
  const float* __restrict__ x1g  = A.p[2];

  // ---------------- persistent register B-fragments (weights, bf16) ----------------
  // H[b][j] = sum_k RBF[b][k] * W1[j][k]  -> B[k][n=j] = w1[n][k]
  s16x8 w1f[4][2];
  {
    const float* w1p = A.p[3 + 4 * w];
    #pragma unroll
    for (int nt = 0; nt < 4; ++nt)
      #pragma unroll
      for (int kt = 0; kt < 2; ++kt) {
        const float* src = w1p + (nt * 16 + ln) * 64 + kt * 32 + hi * 8;
        s16x8 f;
        #pragma unroll
        for (int i = 0; i < 8; ++i) f[i] = f2bf(src[i]);
        w1f[nt][kt] = f;
      }
  }
  float b1v[4];
  {
    const float* b1p = A.p[4 + 4 * w];
    #pragma unroll
    for (int nt = 0; nt < 4; ++nt) b1v[nt] = b1p[nt * 16 + ln];
  }
  // RAD[b][c] = sum_j h[b][j] * W2[c][j] -> B[k=j][n=c] = w2[n][k]
  s16x8 w2f[2][2];
  {
    const float* w2p = A.p[5 + 4 * w];
    #pragma unroll
    for (int nt = 0; nt < 2; ++nt)
      #pragma unroll
      for (int kt = 0; kt < 2; ++kt) {
        const float* src = w2p + (nt * 16 + ln) * 64 + kt * 32 + hi * 8;
        s16x8 f;
        #pragma unroll
        for (int i = 0; i < 8; ++i) f[i] = f2bf(src[i]);
        w2f[nt][kt] = f;
      }
  }
  float b2v[2];
  {
    const float* b2p = A.p[6 + 4 * w];
    #pragma unroll
    for (int nt = 0; nt < 2; ++nt) b2v[nt] = b2p[nt * 16 + ln];
  }

  const float gax = geom[3*a+0], gay = geom[3*a+1], gaz = geom[3*a+2];

  // stage-3 roles: threads 0..191 -> (b-half, channel c3, component i3)
  const bool act3 = (tid < 192);
  const int  t3   = (tid < 96) ? tid : tid - 96;
  const int  bh3  = (tid >= 96) ? 1 : 0;
  const int  c3   = t3 & 31;
  const int  i3   = t3 >> 5;
  const int  j3   = (i3 + 1) % 3;
  const int  k3   = (i3 + 2) % 3;

  float o1a = 0.f, o1b = 0.f, o1c = 0.f, o0a = 0.f, o0b = 0.f;

  for (int t = 0; t < NT; ++t) {
    const int b0 = t * BT;
    __syncthreads();   // previous tile's stage-3 readers done before overwriting LDS

    // ---------------- Phase A: rbf (bf16), unit vectors, transposed x staging ----------------
    {
      const int bb = tid & 31;
      const int rq = tid >> 5;             // 8 groups of 8 rbf centers
      const int bg = b0 + bb;
      const float dx = gax - geom[3*bg+0];
      const float dy = gay - geom[3*bg+1];
      const float dz = gaz - geom[3*bg+2];
      const float r2 = dx*dx + dy*dy + dz*dz;
      const float dij = sqrtf(fmaxf(r2, 1e-8f));
      const float base = dij - STEP * (float)(8 * rq);
      s16x8 pk;
      #pragma unroll
      for (int e = 0; e < 8; ++e) {
        const float d = base - STEP * (float)e;
        pk[e] = f2bf(__expf(-10.f * d * d));
      }
      *(s16x8*)&rbf_s[bb][rq * 8] = pk;
      if (rq == 0) {
        const float inv = 1.0f / sqrtf(r2 + 1e-8f);
        uT[0][bb] = dx * inv; uT[1][bb] = dy * inv; uT[2][bb] = dz * inv;
      }
      #pragma unroll
      for (int s = 0; s < 4; ++s) {
        const int idx = s * 256 + tid;
        x0T[idx & 31][idx >> 5] = x0g[b0 * 32 + idx];
      }
      #pragma unroll
      for (int s = 0; s < 12; ++s) {
        const int idx = s * 256 + tid;
        const int b = idx / 96, r = idx - b * 96;
        x1T[r][b] = x1g[b0 * 96 + idx];
      }
    }
    __syncthreads();

    // ---------------- Stage 1 (per wave = net): H = relu(RBF . W1^T + b1), bf16 MFMA ----------------
    {
      s16x8 af[2][2];
      #pragma unroll
      for (int mt = 0; mt < 2; ++mt)
        #pragma unroll
        for (int kt = 0; kt < 2; ++kt)
          af[mt][kt] = *(const s16x8*)&rbf_s[mt * 16 + ln][kt * 32 + hi * 8];
      f32x4 acc[2][4] = {};
      #pragma unroll
      for (int kt = 0; kt < 2; ++kt)
        #pragma unroll
        for (int mt = 0; mt < 2; ++mt)
          #pragma unroll
          for (int nt = 0; nt < 4; ++nt)
            acc[mt][nt] = __builtin_amdgcn_mfma_f32_16x16x32_bf16(
                af[mt][kt], w1f[nt][kt], acc[mt][nt], 0, 0, 0);
      // bias + relu + cvt -> h_s[w] (own wave writes, own wave reads: no barrier needed)
      #pragma unroll
      for (int mt = 0; mt < 2; ++mt)
        #pragma unroll
        for (int nt = 0; nt < 4; ++nt)
          #pragma unroll
          for (int r = 0; r < 4; ++r)
            h_s[w][mt * 16 + hi * 4 + r][nt * 16 + ln] =
                f2bf(fmaxf(acc[mt][nt][r] + b1v[nt], 0.0f));

      // ---------------- Stage 2: RAD = H . W2^T + b2 -> radT ----------------
      s16x8 a2[2][2];
      #pragma unroll
      for (int mt = 0; mt < 2; ++mt)
        #pragma unroll
        for (int kt = 0; kt < 2; ++kt)
          a2[mt][kt] = *(const s16x8*)&h_s[w][mt * 16 + ln][kt * 32 + hi * 8];
      f32x4 acc2[2][2] = {};
      #pragma unroll
      for (int kt = 0; kt < 2; ++kt)
        #pragma unroll
        for (int mt = 0; mt < 2; ++mt)
          #pragma unroll
          for (int nt = 0; nt < 2; ++nt)
            acc2[mt][nt] = __builtin_amdgcn_mfma_f32_16x16x32_bf16(
                a2[mt][kt], w2f[nt][kt], acc2[mt][nt], 0, 0, 0);
      #pragma unroll
      for (int mt = 0; mt < 2; ++mt)
        #pragma unroll
        for (int nt = 0; nt < 2; ++nt) {
          f32x4 v = acc2[mt][nt];
          #pragma unroll
          for (int r = 0; r < 4; ++r) v[r] += b2v[nt];
          *(f32x4*)&radT[w * 32 + nt * 16 + ln][mt * 16 + hi * 4] = v;
        }
    }
    __syncthreads();

    // ---------------- Stage 3: equivariant neighbor accumulation (vectorized over b) ----------------
    if (act3) {
      const int bB = bh3 * 16;
      #pragma unroll
      for (int bq = 0; bq < 4; ++bq) {
        const int bo = bB + bq * 4;
        const f32x4 r0 = *(const f32x4*)&radT[      c3][bo];
        const f32x4 ra = *(const f32x4*)&radT[32  + c3][bo];
        const f32x4 rb = *(const f32x4*)&radT[64  + c3][bo];
        const f32x4 rc = *(const f32x4*)&radT[96  + c3][bo];
        const f32x4 xv0 = *(const f32x4*)&x0T[c3][bo];
        const f32x4 xi  = *(const f32x4*)&x1T[3 * c3 + i3][bo];
        const f32x4 xj  = *(const f32x4*)&x1T[3 * c3 + j3][bo];
        const f32x4 xk  = *(const f32x4*)&x1T[3 * c3 + k3][bo];
        const f32x4 ui  = *(const f32x4*)&uT[i3][bo];
        const f32x4 uj  = *(const f32x4*)&uT[j3][bo];
        const f32x4 uk  = *(const f32x4*)&uT[k3][bo];
        #pragma unroll
        for (int e = 0; e < 4; ++e) {
          o1b = fmaf(r0[e], xi[e], o1b);                               // out1_b = r0 * x1
          o1a = fmaf(ra[e] * xv0[e], ui[e], o1a);                      // out1_a = u_i * ra * x0
          o1c = fmaf(rc[e], fmaf(uj[e], xk[e], -(uk[e] * xj[e])), o1c); // out1_c = rc * (u x x1)_i
          if (i3 == 0) {
            o0a = fmaf(r0[e], xv0[e], o0a);                            // out0_a = r0 * x0
            const float dot = fmaf(ui[e], xi[e], fmaf(uj[e], xj[e], uk[e] * xk[e]));
            o0b = fmaf(rb[e], dot, o0b);                               // out0_b = rb * (u . x1)
          }
        }
      }
    }
  }

  // ---------------- combine b-half partials and store ----------------
  __syncthreads();
  if (tid >= 96 && tid < 192) {
    const int q = tid - 96;
    scr[q][0] = o1a; scr[q][1] = o1b; scr[q][2] = o1c; scr[q][3] = o0a; scr[q][4] = o0b;
  }
  __syncthreads();
  if (tid < 96) {
    o1a += scr[tid][0]; o1b += scr[tid][1]; o1c += scr[tid][2];
    o0a += scr[tid][3]; o0b += scr[tid][4];
    // output: out0 [512][64][1] then out1 [512][96][3]
    float* o1 = out + NATOM * 64 + a * 288;
    o1[(      c3) * 3 + i3] = o1a;
    o1[(32  + c3) * 3 + i3] = o1b;
    o1[(64  + c3) * 3 + i3] = o1c;
    if (i3 == 0) {
      out[a * 64 + c3]      = o0a;
      out[a * 64 + 32 + c3] = o0b;
    }
  }
}

} // namespace

extern "C" void kernel_launch(void* const* d_in, const int* in_sizes, int n_in,
                              void* d_out, int out_size, void* d_ws, size_t ws_size,
                              hipStream_t stream) {
  (void)in_sizes; (void)n_in; (void)d_ws; (void)ws_size; (void)out_size;
  Ptrs A;
  for (int i = 0; i < 19; ++i) A.p[i] = (const float*)d_in[i];
  tfn_fused<<<dim3(NATOM), dim3(256), 0, stream>>>(A, (float*)d_out);
}